// Round 11
// baseline (207.183 us; speedup 1.0000x reference)
//
#include <hip/hip_runtime.h>
#include <hip/hip_cooperative_groups.h>
#include <hip/hip_bf16.h>
#include <math.h>

namespace cg = cooperative_groups;

#define KIN  2048
#define OKD  1024
#define NB   256
#define OUTF 64
#define KD   16

typedef float f32x4  __attribute__((ext_vector_type(4)));
typedef short bf16x4 __attribute__((ext_vector_type(4)));
typedef short bf16x8 __attribute__((ext_vector_type(8)));
typedef unsigned short u16x8 __attribute__((ext_vector_type(8)));

static __device__ __forceinline__ unsigned short f2bf(float f) {
    union { __hip_bfloat16 b; unsigned short u; } cv;
    cv.b = __float2bfloat16(f);
    return cv.u;
}
static __device__ __forceinline__ u16x8 pack8(float4 a, float4 b) {
    u16x8 r;
    r[0]=f2bf(a.x); r[1]=f2bf(a.y); r[2]=f2bf(a.z); r[3]=f2bf(a.w);
    r[4]=f2bf(b.x); r[5]=f2bf(b.y); r[6]=f2bf(b.z); r[7]=f2bf(b.w);
    return r;
}
static __device__ __forceinline__ float bf2f(unsigned short u) {
    union { unsigned int i; float f; } cv; cv.i = ((unsigned int)u) << 16; return cv.f;
}

// frag layout (16x16x32 bf16): A/B row|col = lane&15, k = 4*(lane>>4)+{0..3} and +16
// C/D: col = lane&15, row = 4*(lane>>4)+reg
static __device__ __forceinline__ bf16x8 load_frag(const unsigned short* lds, int row, int k0) {
    int b0 = (row << 7) + (k0 << 1);
    b0 ^= (row & 7) << 4;                 // XOR swizzle (bank-conflict fix)
    bf16x4 lo = *(const bf16x4*)((const char*)lds + b0);
    bf16x4 hi = *(const bf16x4*)((const char*)lds + (b0 ^ 32)); // +16 k (XOR commutes)
    bf16x8 r;
    r[0]=lo[0]; r[1]=lo[1]; r[2]=lo[2]; r[3]=lo[3];
    r[4]=hi[0]; r[5]=hi[1]; r[6]=hi[2]; r[7]=hi[3];
    return r;
}

// ===================== cooperative megakernel, grid 256 x 256 =====================
__global__ __launch_bounds__(256) void k_mega(
        const float* __restrict__ W, const float* __restrict__ u,
        const float* __restrict__ x,
        float* __restrict__ partial, float* __restrict__ vraw,
        float* __restrict__ nvpart, float* __restrict__ tpart,
        float* __restrict__ P, unsigned short* __restrict__ Wb,
        unsigned short* __restrict__ xb, float* __restrict__ outF) {
    cg::grid_group grid = cg::this_grid();
    __shared__ __align__(16) unsigned char SMEM[16384];
    __shared__ float small_[16];

    int bid = blockIdx.x, tid = threadIdx.x;
    int lane = tid & 63, w = tid >> 6;
    const float4* x4 = (const float4*)x;
    float4* out4 = (float4*)outF;

    // ---------- P0: W cast + W^T u partials; x cast; x -> out ----------
    {
        int c = tid * 8;
        float s[8];
#pragma unroll
        for (int i = 0; i < 8; ++i) s[i] = 0.f;
#pragma unroll
        for (int r = 0; r < 4; ++r) {
            int row = bid * 4 + r;
            const float4* src = (const float4*)(W + (size_t)row * KIN + c);
            float4 f0 = src[0], f1 = src[1];
            *(u16x8*)(Wb + (size_t)row * KIN + c) = pack8(f0, f1);
            float uu = u[row];
            s[0] += f0.x * uu; s[1] += f0.y * uu; s[2] += f0.z * uu; s[3] += f0.w * uu;
            s[4] += f1.x * uu; s[5] += f1.y * uu; s[6] += f1.z * uu; s[7] += f1.w * uu;
        }
        float4* dst = (float4*)(partial + (size_t)bid * KIN + c);
        dst[0] = make_float4(s[0], s[1], s[2], s[3]);
        dst[1] = make_float4(s[4], s[5], s[6], s[7]);

        int g = bid * 256 + tid;                       // 65536 u16x8 of x
        float4 f0 = x4[(size_t)g * 2], f1 = x4[(size_t)g * 2 + 1];
        *((u16x8*)xb + g) = pack8(f0, f1);

#pragma unroll
        for (int p = 0; p < 2; ++p) {                  // 131072 float4 x->out
            int i = bid * 512 + p * 256 + tid;
            int r = i >> 3, cc = i & 7;
            out4[(size_t)r * 24 + cc] = x4[i];
        }
    }
    grid.sync();

    // ---------- P1: vraw[c] = sum over 256 partials; nvpart[bid] ----------
    {
        int c0 = bid * 8 + w * 2;                      // 2 cols per wave
        float a0 = 0.f, a1 = 0.f;
#pragma unroll
        for (int q = 0; q < 4; ++q) {
            const float2 pv = *(const float2*)(partial + (size_t)(lane + 64 * q) * KIN + c0);
            a0 += pv.x; a1 += pv.y;
        }
#pragma unroll
        for (int off = 32; off; off >>= 1) {
            a0 += __shfl_xor(a0, off); a1 += __shfl_xor(a1, off);
        }
        if (lane == 0) {
            vraw[c0] = a0; vraw[c0 + 1] = a1;
            small_[w] = a0 * a0 + a1 * a1;
        }
    }
    __syncthreads();
    if (tid == 0) nvpart[bid] = small_[0] + small_[1] + small_[2] + small_[3];
    grid.sync();

    // ---------- P2: t-dots (4 rows/block) + nv2 (block 0) + MFMA GEMM ----------
    {   // t-path: y_row = Wb[row] . vraw ; tpart[bid] = sum y^2 over 4 rows
        int row = bid * 4 + w;
        const u16x8* W8 = (const u16x8*)(Wb + (size_t)row * KIN);
        const float4* v4 = (const float4*)vraw;
        float s = 0.f;
#pragma unroll
        for (int q = 0; q < 4; ++q) {
            int idx = q * 64 + lane;
            u16x8 a = W8[idx];
            float4 b0 = v4[idx * 2], b1 = v4[idx * 2 + 1];
            s += bf2f(a[0])*b0.x + bf2f(a[1])*b0.y + bf2f(a[2])*b0.z + bf2f(a[3])*b0.w;
            s += bf2f(a[4])*b1.x + bf2f(a[5])*b1.y + bf2f(a[6])*b1.z + bf2f(a[7])*b1.w;
        }
#pragma unroll
        for (int off = 32; off; off >>= 1) s += __shfl_xor(s, off);
        if (lane == 0) small_[w] = s * s;
    }
    __syncthreads();
    if (tid == 0) tpart[bid] = small_[0] + small_[1] + small_[2] + small_[3];
    if (bid == 0) {                                    // nv2 = |vraw|^2
        float nv = nvpart[tid];
#pragma unroll
        for (int off = 32; off; off >>= 1) nv += __shfl_xor(nv, off);
        if (lane == 0) small_[8 + w] = nv;
        __syncthreads();
        if (tid == 0) tpart[256] = small_[8] + small_[9] + small_[10] + small_[11];
    }
    {   // gemm: P = xb * Wb^T, 32x32 tile, 2-phase double buffer
        unsigned short* sAB0 = (unsigned short*)SMEM;  // 2 x 4096 u16
        int c0 = (bid & 31) * 32, n0 = (bid >> 5) * 32;
        const char* gq[2];
        int lqo[2];
#pragma unroll
        for (int q = 0; q < 2; ++q) {
            int ch = q * 4 + w;
            int p = ch * 1024 + lane * 16;
            int rp = p & 4095;
            int row = rp >> 7;
            int off = (rp & 127) ^ ((row & 7) << 4);   // inverse-swizzled source
            const unsigned short* base = (p < 4096) ? xb : Wb;
            int grow = (p < 4096) ? (n0 + row) : (c0 + row);
            gq[q] = (const char*)(base + (size_t)grow * KIN) + off;
            lqo[q] = ch * 512;
        }
        int g = lane >> 4, cl = lane & 15;
        int wy = w >> 1, wx = w & 1;
        f32x4 acc;
#pragma unroll
        for (int r = 0; r < 4; ++r) acc[r] = 0.f;

        __syncthreads();                               // SMEM now free for staging
#pragma unroll
        for (int q = 0; q < 2; ++q)
            __builtin_amdgcn_global_load_lds(
                (const __attribute__((address_space(1))) unsigned int*)(gq[q]),
                (__attribute__((address_space(3))) unsigned int*)(sAB0 + lqo[q]), 16, 0, 0);
        __syncthreads();

        for (int t = 0; t < 32; ++t) {
            int cur = t & 1;
            unsigned short* cbuf = sAB0 + (cur << 12);
            unsigned short* pbuf = sAB0 + ((cur ^ 1) << 12);
            if (t < 31) {
                int kb = (t + 1) * 128;
#pragma unroll
                for (int q = 0; q < 2; ++q)
                    __builtin_amdgcn_global_load_lds(
                        (const __attribute__((address_space(1))) unsigned int*)(gq[q] + kb),
                        (__attribute__((address_space(3))) unsigned int*)(pbuf + lqo[q]), 16, 0, 0);
            }
            const unsigned short* sA = cbuf;
            const unsigned short* sB = cbuf + 2048;
#pragma unroll
            for (int s = 0; s < 2; ++s) {
                int k0 = s * 32 + 4 * g;
                bf16x8 af = load_frag(sA, wy * 16 + cl, k0);
                bf16x8 bf = load_frag(sB, wx * 16 + cl, k0);
                acc = __builtin_amdgcn_mfma_f32_16x16x32_bf16(af, bf, acc, 0, 0, 0);
            }
            __syncthreads();
        }
        int col = c0 + wx * 16 + cl;
        int row0 = n0 + wy * 16 + 4 * g;
#pragma unroll
        for (int r = 0; r < 4; ++r)
            P[(size_t)(row0 + r) * OKD + col] = acc[r];
    }
    grid.sync();

    // ---------- P3: pair + sigma + ob -> out scatter ----------
    {
        float* sm = (float*)SMEM;                      // 4096 floats
        int o = bid & 63, h = bid >> 6;

        float tv = tpart[tid];                         // 256 partials
#pragma unroll
        for (int off = 32; off; off >>= 1) tv += __shfl_xor(tv, off);
        if (lane == 0) small_[w] = tv;

        const float4* M4 = (const float4*)P;
        float4* sm4 = (float4*)sm;
#pragma unroll
        for (int tq = 0; tq < 4; ++tq) {
            int idx = tid + tq * 256;                  // 1024 float4
            int j = idx >> 2, k4 = idx & 3;
            sm4[j * 4 + (k4 ^ (j & 3))] = M4[(size_t)j * 256 + o * 4 + k4];
        }
        __syncthreads();

        float ssum = small_[0] + small_[1] + small_[2] + small_[3];
        float nv2 = tpart[256];
        float ssq = ssum / nv2;                        // = |W v|^2
        float invs = (sqrtf(ssq) + 1e-12f) / ssq;      // = 1/sigma

        int nl = tid >> 2, jc = tid & 3;
        int n = h * 64 + nl;
        int nx = (n & 3) << 2;
        float r[KD];
#pragma unroll
        for (int k = 0; k < KD; ++k) r[k] = sm[n * 16 + (k ^ nx)];
        float acc = 0.f;
        for (int jj = 0; jj < 64; ++jj) {
            int j = jj * 4 + jc;
            int base = j * 16, jx = (j & 3) << 2;
            float d = 0.f;
#pragma unroll
            for (int k = 0; k < KD; ++k) d += fabsf(r[k] - sm[base + (k ^ jx)]);
            acc += __expf(-d * invs);
        }
        acc += __shfl_xor(acc, 1);
        acc += __shfl_xor(acc, 2);
        __syncthreads();                               // sm dead; reuse for ob
        if (jc == 0) sm[nl] = acc - 1.0f;
        __syncthreads();
#pragma unroll
        for (int s5 = 0; s5 < 16; ++s5) {              // 4096 scalar stores
            int idx = s5 * 256 + tid;
            int n2 = idx >> 6, l = idx & 63;
            outF[(size_t)((h * 64 + n2) * 64 + l) * 96 + 32 + o] = sm[n2];
        }
    }
}

extern "C" void kernel_launch(void* const* d_in, const int* in_sizes, int n_in,
                              void* d_out, int out_size, void* d_ws, size_t ws_size,
                              hipStream_t stream) {
    const float* x = (const float*)d_in[0];   // 256*64*32
    const float* W = (const float*)d_in[1];   // 1024*2048
    // d_in[2] = bias: cancels exactly in m[i]-m[j] -> unused
    const float* u = (const float*)d_in[3];   // 1024

    float* ws = (float*)d_ws;
    float* partial = ws;                       // 524288
    float* vraw    = ws + 524288;              // 2048
    float* nvpart  = ws + 526336;              // 256
    float* tpart   = ws + 526592;              // 257 (+pad)
    float* P       = ws + 528384;              // 262144
    unsigned short* Wb = (unsigned short*)(ws + 790528);    // 2M u16 (4MB)
    unsigned short* xb = (unsigned short*)(ws + 1839104);   // 512K u16 (1MB)
    float* outF = (float*)d_out;
    // total 2101248 floats = 8.4 MB, all disjoint

    void* args[] = { (void*)&W, (void*)&u, (void*)&x, (void*)&partial,
                     (void*)&vraw, (void*)&nvpart, (void*)&tpart, (void*)&P,
                     (void*)&Wb, (void*)&xb, (void*)&outF };
    hipLaunchCooperativeKernel((void*)k_mega, dim3(256), dim3(256), args, 0, stream);
}

// Round 13
// 93.676 us; speedup vs baseline: 2.2117x; 2.2117x over previous
//
#include <hip/hip_runtime.h>
#include <hip/hip_bf16.h>
#include <math.h>

#define KIN  2048
#define OKD  1024
#define NB   256
#define OUTF 64
#define KD   16

typedef float f32x4  __attribute__((ext_vector_type(4)));
typedef short bf16x4 __attribute__((ext_vector_type(4)));
typedef short bf16x8 __attribute__((ext_vector_type(8)));
typedef unsigned short u16x8 __attribute__((ext_vector_type(8)));

static __device__ __forceinline__ unsigned short f2bf(float f) {
    union { __hip_bfloat16 b; unsigned short u; } cv;
    cv.b = __float2bfloat16(f);
    return cv.u;
}
static __device__ __forceinline__ u16x8 pack8(float4 a, float4 b) {
    u16x8 r;
    r[0]=f2bf(a.x); r[1]=f2bf(a.y); r[2]=f2bf(a.z); r[3]=f2bf(a.w);
    r[4]=f2bf(b.x); r[5]=f2bf(b.y); r[6]=f2bf(b.z); r[7]=f2bf(b.w);
    return r;
}
static __device__ __forceinline__ float bf2f(unsigned short u) {
    union { unsigned int i; float f; } cv; cv.i = ((unsigned int)u) << 16; return cv.f;
}

// ==== K1 (grid 416): bid<256: W cast + 4-row partials of W^T u
//                     256..287: x -> bf16 cast
//                     288..415: x -> out copy (c<8 float4 of each 24-float4 row)
__global__ __launch_bounds__(256) void k_stage1(const float* __restrict__ W,
        const float* __restrict__ u, const float* __restrict__ x,
        float* __restrict__ partial, unsigned short* __restrict__ Wb,
        unsigned short* __restrict__ xb, float4* __restrict__ out4) {
    int bid = blockIdx.x, tid = threadIdx.x;
    if (bid < 256) {
        int row0 = bid * 4;
        int c = tid * 8;
        float s[8];
#pragma unroll
        for (int i = 0; i < 8; ++i) s[i] = 0.f;
#pragma unroll
        for (int r = 0; r < 4; ++r) {
            int row = row0 + r;
            const float4* src = (const float4*)(W + (size_t)row * KIN + c);
            float4 f0 = src[0], f1 = src[1];
            *(u16x8*)(Wb + (size_t)row * KIN + c) = pack8(f0, f1);
            float uu = u[row];
            s[0] += f0.x * uu; s[1] += f0.y * uu; s[2] += f0.z * uu; s[3] += f0.w * uu;
            s[4] += f1.x * uu; s[5] += f1.y * uu; s[6] += f1.z * uu; s[7] += f1.w * uu;
        }
        float4* dst = (float4*)(partial + (size_t)bid * KIN + c);
        dst[0] = make_float4(s[0], s[1], s[2], s[3]);
        dst[1] = make_float4(s[4], s[5], s[6], s[7]);
    } else if (bid < 288) {
        int xc = bid - 256;
        const float4* x4 = (const float4*)x;
#pragma unroll
        for (int p = 0; p < 8; ++p) {
            int g = xc * 2048 + p * 256 + tid;      // 32*2048 = 65536 packs of 8
            float4 f0 = x4[(size_t)g * 2], f1 = x4[(size_t)g * 2 + 1];
            *((u16x8*)xb + g) = pack8(f0, f1);
        }
    } else {
        int xo = bid - 288;
        const float4* x4 = (const float4*)x;
#pragma unroll
        for (int p = 0; p < 4; ++p) {
            int i = xo * 1024 + p * 256 + tid;      // 128*1024 = 131072 float4 of x
            int r = i >> 3, c = i & 7;
            out4[(size_t)r * 24 + c] = x4[i];
        }
    }
}

// ==== K2 (grid 32): reduce partial[256][2048] -> partial4[4][2048]
__global__ __launch_bounds__(256) void k_vred(const float* __restrict__ partial,
                                              float* __restrict__ partial4) {
    int bid = blockIdx.x, tid = threadIdx.x;
    int bg = bid >> 3, cg = bid & 7;          // bg: 64-row group, cg: 256-col group
    int col = cg * 256 + tid;
    float a = 0.f;
#pragma unroll 8
    for (int i = 0; i < 64; ++i)
        a += partial[(size_t)(bg * 64 + i) * KIN + col];
    partial4[bg * KIN + col] = a;
}

// ==== K3 (grid 1024): bid<512: MFMA GEMM P_half = xb * Wb^T (split-K=2),
//                               32x32 tile, 2-phase double-buffered pipeline
//                      bid>=512: tpart[tb] = (r0.vraw)^2+(r1.vraw)^2; tpart[512]=|vraw|^2
// frag layout (16x16x32 bf16): A/B row|col = lane&15, k = 4*(lane>>4)+{0..3} and +16
// C/D: col = lane&15, row = 4*(lane>>4)+reg
static __device__ __forceinline__ bf16x8 load_frag(const unsigned short* lds, int row, int k0) {
    int b0 = (row << 7) + (k0 << 1);
    b0 ^= (row & 7) << 4;                 // XOR swizzle (bank-conflict fix)
    bf16x4 lo = *(const bf16x4*)((const char*)lds + b0);
    bf16x4 hi = *(const bf16x4*)((const char*)lds + (b0 ^ 32)); // +16 k (XOR commutes)
    bf16x8 r;
    r[0]=lo[0]; r[1]=lo[1]; r[2]=lo[2]; r[3]=lo[3];
    r[4]=hi[0]; r[5]=hi[1]; r[6]=hi[2]; r[7]=hi[3];
    return r;
}

__global__ __launch_bounds__(256) void k_tg(const unsigned short* __restrict__ xb,
        const unsigned short* __restrict__ Wb, const float* __restrict__ partial4,
        float* __restrict__ tpart, float* __restrict__ P) {
    __shared__ unsigned short sAB[2][4096];   // 2 x (A 32x64 | B 32x64) bf16
    __shared__ float part[4], part2s[4];
    int bid = blockIdx.x, tid = threadIdx.x;
    int lane = tid & 63, w = tid >> 6;

    if (bid >= 512) {
        // ---- t-path: dot W row with vraw (= sum of 4 partial4 rows) ----
        int tb = bid - 512;                    // 0..511, 2 rows each
        int row = tb * 2 + (w >> 1);
        int h = w & 1;
        const u16x8* W8 = (const u16x8*)(Wb + (size_t)row * KIN + h * 1024);
        const float4* p0 = (const float4*)(partial4 + h * 1024);
        const float4* p1 = (const float4*)(partial4 + KIN + h * 1024);
        const float4* p2 = (const float4*)(partial4 + 2 * KIN + h * 1024);
        const float4* p3 = (const float4*)(partial4 + 3 * KIN + h * 1024);
        float s = 0.f, s2 = 0.f;
#pragma unroll
        for (int q = 0; q < 2; ++q) {
            int idx = q * 64 + lane;
            u16x8 a = W8[idx];
#pragma unroll
            for (int e = 0; e < 2; ++e) {
                float4 a0 = p0[idx * 2 + e], b0 = p1[idx * 2 + e];
                float4 c0 = p2[idx * 2 + e], d0 = p3[idx * 2 + e];
                float v0 = a0.x + b0.x + c0.x + d0.x;
                float v1 = a0.y + b0.y + c0.y + d0.y;
                float v2 = a0.z + b0.z + c0.z + d0.z;
                float v3 = a0.w + b0.w + c0.w + d0.w;
                s += bf2f(a[e*4+0])*v0 + bf2f(a[e*4+1])*v1
                   + bf2f(a[e*4+2])*v2 + bf2f(a[e*4+3])*v3;
                s2 += v0*v0 + v1*v1 + v2*v2 + v3*v3;
            }
        }
#pragma unroll
        for (int off = 32; off; off >>= 1) { s += __shfl_xor(s, off); s2 += __shfl_xor(s2, off); }
        if (lane == 0) { part[w] = s; part2s[w] = s2; }
        __syncthreads();
        if (tid == 0) {
            float r0 = part[0] + part[1], r1 = part[2] + part[3];
            tpart[tb] = r0 * r0 + r1 * r1;
            if (tb == 0) tpart[512] = part2s[0] + part2s[1];  // |vraw|^2 (waves 0,1 = row0)
        }
        return;
    }

    // ---- gemm path: split-K=2 ----
    int tile = bid & 255, kc = bid >> 8;       // kc in {0,1}
    int c0 = (tile & 31) * 32, n0 = (tile >> 5) * 32;

    const char* gq[2];
    int lqo[2];
#pragma unroll
    for (int q = 0; q < 2; ++q) {
        int ch = q * 4 + w;
        int p = ch * 1024 + lane * 16;     // byte pos in 8KB tile region
        int rp = p & 4095;
        int row = rp >> 7;                 // 128B per row (64 bf16)
        int off = (rp & 127) ^ ((row & 7) << 4);   // inverse-swizzled source
        const unsigned short* base = (p < 4096) ? xb : Wb;
        int grow = (p < 4096) ? (n0 + row) : (c0 + row);
        gq[q] = (const char*)(base + (size_t)grow * KIN + kc * 1024) + off;
        lqo[q] = ch * 512;                 // u16 offset within one buffer
    }

    int g = lane >> 4, cl = lane & 15;
    int wy = w >> 1, wx = w & 1;
    f32x4 acc;
#pragma unroll
    for (int r = 0; r < 4; ++r) acc[r] = 0.f;

    // prologue: stage tile 0 into buf0
#pragma unroll
    for (int q = 0; q < 2; ++q)
        __builtin_amdgcn_global_load_lds(
            (const __attribute__((address_space(1))) unsigned int*)(gq[q]),
            (__attribute__((address_space(3))) unsigned int*)(&sAB[0][lqo[q]]), 16, 0, 0);
    __syncthreads();

    for (int t = 0; t < 16; ++t) {
        int cur = t & 1;
        if (t < 15) {
            int kb = (t + 1) * 128;
#pragma unroll
            for (int q = 0; q < 2; ++q)
                __builtin_amdgcn_global_load_lds(
                    (const __attribute__((address_space(1))) unsigned int*)(gq[q] + kb),
                    (__attribute__((address_space(3))) unsigned int*)(&sAB[cur ^ 1][lqo[q]]), 16, 0, 0);
        }
        const unsigned short* sA = sAB[cur];
        const unsigned short* sB = sAB[cur] + 2048;
#pragma unroll
        for (int s = 0; s < 2; ++s) {
            int k0 = s * 32 + 4 * g;
            bf16x8 af = load_frag(sA, wy * 16 + cl, k0);
            bf16x8 bf = load_frag(sB, wx * 16 + cl, k0);
            acc = __builtin_amdgcn_mfma_f32_16x16x32_bf16(af, bf, acc, 0, 0, 0);
        }
        __syncthreads();   // drains vmcnt (next-tile stage) + lgkm; WAR-safe
    }

    int col = c0 + wx * 16 + cl;
    int row0 = n0 + wy * 16 + 4 * g;
    float* Pk = P + (size_t)kc * (NB * OKD);
#pragma unroll
    for (int r = 0; r < 4; ++r)
        Pk[(size_t)(row0 + r) * OKD + col] = acc[r];
}

// ==== K4 (grid 64 x 8): ob[n,o] = sum_j exp(-invs * sum_k |m[n,o,k]-m[j,o,k]|) - 1
//      m = P0 + P1 (split-K halves summed during LDS staging)
__global__ __launch_bounds__(256) void k_pair(const float* __restrict__ P,
        const float* __restrict__ tpart, float* __restrict__ ob) {
    __shared__ float sm[NB * KD];   // 16 KB, XOR-swizzled by row
    __shared__ float sred[4];
    int o = blockIdx.x, tid = threadIdx.x;

    // sigma partial reduce (pre-barrier)
    float tv = tpart[tid] + tpart[tid + 256];
#pragma unroll
    for (int off = 32; off; off >>= 1) tv += __shfl_xor(tv, off);
    if ((tid & 63) == 0) sred[tid >> 6] = tv;

    const float4* M4 = (const float4*)P;
    float4* sm4 = (float4*)sm;
#pragma unroll
    for (int tq = 0; tq < 4; ++tq) {
        int idx = tid + tq * 256;          // 1024 float4
        int j = idx >> 2, k4 = idx & 3;
        float4 a = M4[(size_t)j * 256 + o * 4 + k4];
        float4 b = M4[(size_t)65536 + j * 256 + o * 4 + k4];   // P1 half
        sm4[j * 4 + (k4 ^ (j & 3))] =
            make_float4(a.x + b.x, a.y + b.y, a.z + b.z, a.w + b.w);
    }
    __syncthreads();

    float ssum = sred[0] + sred[1] + sred[2] + sred[3];
    float nv2 = tpart[512];
    float ssq = ssum / nv2;                       // = |W v|^2
    float invs = (sqrtf(ssq) + 1e-12f) / ssq;     // = 1/sigma

    int n = blockIdx.y * 32 + (tid >> 3);
    int jc = tid & 7;
    int nx = (n & 3) << 2;
    float r[KD];
#pragma unroll
    for (int k = 0; k < KD; ++k) r[k] = sm[n * 16 + (k ^ nx)];
    float acc = 0.f;
    for (int jj = 0; jj < 32; ++jj) {
        int j = jj * 8 + jc;
        int base = j * 16, jx = (j & 3) << 2;
        float d = 0.f;
#pragma unroll
        for (int k = 0; k < KD; ++k) d += fabsf(r[k] - sm[base + (k ^ jx)]);
        acc += __expf(-d * invs);
    }
    acc += __shfl_xor(acc, 1);
    acc += __shfl_xor(acc, 2);
    acc += __shfl_xor(acc, 4);
    if (jc == 0) ob[n * OUTF + o] = acc - 1.0f;
}

// ==== K5 (grid 256): out[n,l, 32..96) = ob[n,:]  (16 float4 of each 24-float4 row)
__global__ void k_obout(const float* __restrict__ ob, float4* __restrict__ out4) {
    int bid = blockIdx.x, tid = threadIdx.x;
    const float4* ob4 = (const float4*)ob;
#pragma unroll
    for (int p = 0; p < 4; ++p) {
        int i = bid * 1024 + p * 256 + tid;     // 256*1024 = 262144 = 16384 rows x 16
        int r = i >> 4, c2 = i & 15;
        out4[(size_t)r * 24 + 8 + c2] = ob4[(r >> 6) * 16 + c2];
    }
}

extern "C" void kernel_launch(void* const* d_in, const int* in_sizes, int n_in,
                              void* d_out, int out_size, void* d_ws, size_t ws_size,
                              hipStream_t stream) {
    const float* x = (const float*)d_in[0];   // 256*64*32
    const float* W = (const float*)d_in[1];   // 1024*2048
    // d_in[2] = bias: cancels exactly in m[i]-m[j] -> unused
    const float* u = (const float*)d_in[3];   // 1024

    float* ws = (float*)d_ws;
    float* partial  = ws;                   // 256*2048 = 524288  (K1 -> K2, dies)
    float* P        = ws;                   // 2 x 262144 (K3 -> K4), aliases dead partial
    float* partial4 = ws + 524288;          // 4*2048 = 8192
    float* tpart    = ws + 532480;          // 513 (tpart[512] = |vraw|^2), pad to 1024
    float* ob       = ws + 533504;          // 16384
    unsigned short* Wb = (unsigned short*)(ws + 549888);   // 2M bf16 (4MB)
    unsigned short* xb = (unsigned short*)(ws + 1598464);  // 512K bf16 (1MB)
    // total 1860608 floats = 7.1 MB

    k_stage1<<<416,  256, 0, stream>>>(W, u, x, partial, Wb, xb, (float4*)d_out);
    k_vred  <<<32,   256, 0, stream>>>(partial, partial4);
    k_tg    <<<1024, 256, 0, stream>>>(xb, Wb, partial4, tpart, P);
    k_pair  <<<dim3(64, 8), 256, 0, stream>>>(P, tpart, ob);
    k_obout <<<256,  256, 0, stream>>>(ob, (float4*)d_out);
}